// Round 15
// baseline (302.793 us; speedup 1.0000x reference)
//
#include <hip/hip_runtime.h>
#include <cfloat>
#include <math.h>

// Problem constants
#define N_TEXT  226
#define N_IMG   5400
#define N_TOKEN 5626
#define HEAD_STRIDE 31651876u   // N_TOKEN*N_TOKEN
#define HEAD_F4     7912969u    // HEAD_STRIDE/4
#define TOTAL_ELEMS 126607504u  // 4 * HEAD_STRIDE
#define NTILE 6966              // 27^2+36^2+45^2+54^2

// f32(1/15): XLA rewrites divide-by-constant into multiply-by-reciprocal.
#define RCP15 0x1.111112p-4f

typedef float f32x4 __attribute__((ext_vector_type(4)));
typedef float f32x2 __attribute__((ext_vector_type(2)));

// Locked bit-exact arithmetic (verified r9/r11/r14, absmax=0):
//   scale = fl32(delta*fl32(1/15)); safe = scale==0?1:scale;
//   recip = fl32(1/safe); q = clip(roundeven(fl32(x*recip)),0,15);
//   out = fl32(q*scale).
__device__ __forceinline__ float fq1(float x, float recip, float scale) {
    float q = rintf(__fmul_rn(x, recip));
    q = fminf(fmaxf(q, 0.0f), 15.0f);
    return __fmul_rn(q, scale);
}

// ---------------------------------------------------------------------------
// K1 (per head): per-tile block max via flat aligned-f4 sweep with edge
// masking (r14-validated). Block owns its tile; writes {scale, recip}.
// ---------------------------------------------------------------------------
template <int BW, int NB, int BASE, int HEAD>
__global__ __launch_bounds__(256)
void k1h(const float* __restrict__ in, float2* __restrict__ scales) {
    constexpr int NQ   = BW / 4 + 1;     // 51 / 38 / 31 / 26
    constexpr int TOTQ = BW * NQ;

    const int local = blockIdx.x;
    const int bi = local / NB;
    const int bj = local - bi * NB;
    const unsigned base = (unsigned)HEAD * HEAD_STRIDE
                        + (unsigned)(N_TEXT + bi * BW) * N_TOKEN
                        + (unsigned)(N_TEXT + bj * BW);
    const int tid = threadIdx.x;

    float m = 0.0f;                       // inputs are >= 0
    for (int i = tid; i < TOTQ; i += 256) {
        const int r = i / NQ;             // compile-time divisor
        const int k = i - r * NQ;
        const unsigned rowbase = base + (unsigned)r * N_TOKEN;
        const int s = (int)(rowbase & 3u);            // 0 or 2
        const unsigned a0 = rowbase - s + (unsigned)(k << 2);
        if (a0 + 4u <= TOTAL_ELEMS) {                 // tail guard
            f32x4 v = *(const f32x4*)(in + a0);
            const int c0 = (k << 2) - s;              // tile-rel col of v.x
            m = fmaxf(m, (c0 >= 0 && c0 < BW)         ? v.x : 0.0f);
            m = fmaxf(m, (c0 + 1 >= 0 && c0 + 1 < BW) ? v.y : 0.0f);
            m = fmaxf(m, (c0 + 2 < BW)                ? v.z : 0.0f);
            m = fmaxf(m, (c0 + 3 < BW)                ? v.w : 0.0f);
        }
    }
    #pragma unroll
    for (int o = 32; o > 0; o >>= 1)
        m = fmaxf(m, __shfl_xor(m, o));
    __shared__ float sm[4];
    if ((tid & 63) == 0) sm[tid >> 6] = m;
    __syncthreads();
    if (tid == 0) {
        const float delta = fmaxf(fmaxf(sm[0], sm[1]), fmaxf(sm[2], sm[3]));
        const float scale = __fmul_rn(delta, RCP15);
        const float safe  = (scale == 0.0f) ? 1.0f : scale;
        const float recip = __fdiv_rn(1.0f, safe);
        scales[BASE + local] = (float2){scale, recip};
    }
}

// ---------------------------------------------------------------------------
// K2 (per head): linear float4 sweep, reversed within the head so the first
// reads hit the lines K1(h) touched last. Body validated bit-exact (r11/r14).
// ---------------------------------------------------------------------------
template <int BW, int NB, int BASE>
__device__ __forceinline__ void quant_f4(const float* __restrict__ hin,
                                         float* __restrict__ hout,
                                         const float2* __restrict__ scales,
                                         unsigned e, unsigned r, unsigned c) {
    f32x4 v = *(const f32x4*)(hin + e);
    if (r < N_TEXT) { *(f32x4*)(hout + e) = v; return; }          // text rows
    const unsigned bi = (r - N_TEXT) / BW;
    if (c == 5624u) {                                              // row wrap
        const float2 sr = scales[BASE + bi * NB + (NB - 1)];
        v.x = fq1(v.x, sr.y, sr.x);
        v.y = fq1(v.y, sr.y, sr.x);
        *(f32x4*)(hout + e) = v; return;
    }
    if (c + 3u < N_TEXT) { *(f32x4*)(hout + e) = v; return; }      // c<=222
    if (c == 224u) {                                               // text|image
        const float2 sr = scales[BASE + bi * NB];
        v.z = fq1(v.z, sr.y, sr.x);
        v.w = fq1(v.w, sr.y, sr.x);
        *(f32x4*)(hout + e) = v; return;
    }
    const unsigned ic  = c - N_TEXT;
    const unsigned bj0 = ic / BW;
    const unsigned bj3 = (ic + 3u) / BW;
    const float2 s0 = scales[BASE + bi * NB + bj0];
    if (bj0 == bj3) {
        v.x = fq1(v.x, s0.y, s0.x);
        v.y = fq1(v.y, s0.y, s0.x);
        v.z = fq1(v.z, s0.y, s0.x);
        v.w = fq1(v.w, s0.y, s0.x);
    } else {                                                       // tile edge
        const float2 s1 = scales[BASE + bi * NB + bj3];
        const unsigned mm = bj3 * BW - ic;
        const float2 sy = (1u < mm) ? s0 : s1;
        const float2 sz = (2u < mm) ? s0 : s1;
        v.x = fq1(v.x, s0.y, s0.x);
        v.y = fq1(v.y, sy.y, sy.x);
        v.z = fq1(v.z, sz.y, sz.x);
        v.w = fq1(v.w, s1.y, s1.x);
    }
    *(f32x4*)(hout + e) = v;
}

template <int BW, int NB, int BASE, int HEAD>
__global__ __launch_bounds__(256)
void k2h(const float* __restrict__ in, float* __restrict__ out,
         const float2* __restrict__ scales) {
    const unsigned i = blockIdx.x * 256u + threadIdx.x;
    if (i >= HEAD_F4) return;
    const unsigned fi = HEAD_F4 - 1u - i;      // reversed within head
    const unsigned e  = fi * 4u;
    const unsigned r  = e / 5626u;
    const unsigned c  = e - r * 5626u;
    const float* hin  = in  + (size_t)HEAD * HEAD_STRIDE;
    float*       hout = out + (size_t)HEAD * HEAD_STRIDE;
    quant_f4<BW, NB, BASE>(hin, hout, scales, e, r, c);
}

extern "C" void kernel_launch(void* const* d_in, const int* in_sizes, int n_in,
                              void* d_out, int out_size, void* d_ws, size_t ws_size,
                              hipStream_t stream) {
    const float* x = (const float*)d_in[0];
    float* out     = (float*)d_out;
    float2* scales = (float2*)d_ws;                            // 6966 float2
    const unsigned g2 = (HEAD_F4 + 255u) / 256u;               // 30911

    // Per-head pipeline: K1(h) then K2(h) while head h is L3-resident.
    k1h<200, 27, 0,    0><<< 729, 256, 0, stream>>>(x, scales);
    k2h<200, 27, 0,    0><<<g2,   256, 0, stream>>>(x, out, scales);
    k1h<150, 36, 729,  1><<<1296, 256, 0, stream>>>(x, scales);
    k2h<150, 36, 729,  1><<<g2,   256, 0, stream>>>(x, out, scales);
    k1h<120, 45, 2025, 2><<<2025, 256, 0, stream>>>(x, scales);
    k2h<120, 45, 2025, 2><<<g2,   256, 0, stream>>>(x, out, scales);
    k1h<100, 54, 4050, 3><<<2916, 256, 0, stream>>>(x, scales);
    k2h<100, 54, 4050, 3><<<g2,   256, 0, stream>>>(x, out, scales);
}

// Round 16
// 252.293 us; speedup vs baseline: 1.2002x; 1.2002x over previous
//
#include <hip/hip_runtime.h>
#include <cfloat>
#include <math.h>

// Problem constants
#define N_TEXT  226
#define N_IMG   5400
#define N_TOKEN 5626
#define HEAD_STRIDE 31651876u   // N_TOKEN*N_TOKEN
#define TOTAL_ELEMS 126607504u  // 4 * HEAD_STRIDE
#define NTILE 6966              // 27^2+36^2+45^2+54^2
#define TEXT_BLOCKS 512
#define NA4  317869             // f4 slots in region A per head (226*5626/4)
#define NQB  57                 // aligned f4 slots covering cols [0,226) per row
#define NA_ALL (4 * NA4)        // 1271476
#define NB_ALL (4 * 5400 * NQB) // 1231200

// f32(1/15): XLA rewrites divide-by-constant into multiply-by-reciprocal.
#define RCP15 0x1.111112p-4f

typedef float f32x4 __attribute__((ext_vector_type(4)));

// Locked bit-exact arithmetic (verified r9/r11/r14, absmax=0):
//   scale = fl32(delta*fl32(1/15)); safe = scale==0?1:scale;
//   recip = fl32(1/safe); q = clip(roundeven(fl32(x*recip)),0,15);
//   out = fl32(q*scale).
__device__ __forceinline__ float fq1(float x, float recip, float scale) {
    float q = rintf(__fmul_rn(x, recip));
    q = fminf(fmaxf(q, 0.0f), 15.0f);
    return __fmul_rn(q, scale);
}

// ---------------------------------------------------------------------------
// Fused per-tile quantization: load tile into registers (masked aligned-f4,
// r14-validated coverage) accumulating max; block-reduce; quantize registers;
// masked store. Input read ONCE; no scale LUT, no atomics, no second pass.
// ---------------------------------------------------------------------------
template <int BW, int NB, int R>
__device__ __forceinline__ void tile_fused(const float* __restrict__ in,
                                           float* __restrict__ out,
                                           int local, int head) {
    constexpr int NQ   = BW / 4 + 1;     // 51 / 38 / 31 / 26
    constexpr int TOTQ = BW * NQ;

    const int bi = local / NB;
    const int bj = local - bi * NB;
    const unsigned base = (unsigned)head * HEAD_STRIDE
                        + (unsigned)(N_TEXT + bi * BW) * N_TOKEN
                        + (unsigned)(N_TEXT + bj * BW);
    const int tid = threadIdx.x;

    // ---- load + max accumulate (registers) ----
    f32x4 vr[R];
    float m = 0.0f;                       // inputs are >= 0
    #pragma unroll
    for (int j = 0; j < R; ++j) {
        const int i = tid + j * 1024;
        const int r = i / NQ;             // compile-time divisor
        const int k = i - r * NQ;
        const unsigned rowbase = base + (unsigned)r * N_TOKEN;
        const int s = (int)(rowbase & 3u);            // 0 or 2
        const unsigned a0 = rowbase - s + (unsigned)(k << 2);
        const bool act = (i < TOTQ) && (a0 + 4u <= TOTAL_ELEMS);
        vr[j] = act ? *(const f32x4*)(in + a0) : (f32x4){0.f, 0.f, 0.f, 0.f};
        if (act) {
            const int c0 = (k << 2) - s;              // tile-rel col of v.x
            m = fmaxf(m, (c0 >= 0 && c0 < BW)         ? vr[j].x : 0.0f);
            m = fmaxf(m, (c0 + 1 >= 0 && c0 + 1 < BW) ? vr[j].y : 0.0f);
            m = fmaxf(m, (c0 + 2 < BW)                ? vr[j].z : 0.0f);
            m = fmaxf(m, (c0 + 3 < BW)                ? vr[j].w : 0.0f);
        }
    }

    // ---- block reduce (16 waves) ----
    #pragma unroll
    for (int o = 32; o > 0; o >>= 1)
        m = fmaxf(m, __shfl_xor(m, o));
    __shared__ float sm[16];
    if ((tid & 63) == 0) sm[tid >> 6] = m;
    __syncthreads();
    float delta = sm[0];
    #pragma unroll
    for (int w = 1; w < 16; ++w) delta = fmaxf(delta, sm[w]);

    const float scale = __fmul_rn(delta, RCP15);
    const float safe  = (scale == 0.0f) ? 1.0f : scale;
    const float recip = __fdiv_rn(1.0f, safe);

    // ---- quantize registers + masked store ----
    #pragma unroll
    for (int j = 0; j < R; ++j) {
        const int i = tid + j * 1024;
        const int r = i / NQ;
        const int k = i - r * NQ;
        const unsigned rowbase = base + (unsigned)r * N_TOKEN;
        const int s = (int)(rowbase & 3u);
        const unsigned a0 = rowbase - s + (unsigned)(k << 2);
        if (i >= TOTQ || a0 + 4u > TOTAL_ELEMS) continue;
        const int c0 = (k << 2) - s;
        f32x4 v = vr[j];
        v.x = fq1(v.x, recip, scale);
        v.y = fq1(v.y, recip, scale);
        v.z = fq1(v.z, recip, scale);
        v.w = fq1(v.w, recip, scale);
        if (c0 >= 0 && c0 + 3 < BW) {
            *(f32x4*)(out + a0) = v;                  // interior slot
        } else {                                      // edge: per-elem mask
            if (c0 >= 0 && c0 < BW)         out[a0]     = v.x;
            if (c0 + 1 >= 0 && c0 + 1 < BW) out[a0 + 1] = v.y;
            if (c0 + 2 < BW)                out[a0 + 2] = v.z;  // c0+2>=0 always
            if (c0 + 3 < BW)                out[a0 + 3] = v.w;
        }
    }
}

// ---------------------------------------------------------------------------
// Text copy (grid-stride): region A = rows [0,226) full width (contiguous f4
// per head); region B = rows [226,5626) cols [0,226) via masked aligned-f4.
// Reads may touch image cols (input is read-only: no race); writes masked to
// text cols only -> disjoint from tile writes.
// ---------------------------------------------------------------------------
__device__ __forceinline__ void text_copy(const float* __restrict__ in,
                                          float* __restrict__ out, int cb) {
    const int tid0   = cb * 1024 + threadIdx.x;
    const int stride = TEXT_BLOCKS * 1024;

    for (int idx = tid0; idx < NA_ALL; idx += stride) {
        const int head = idx / NA4;
        const int rem  = idx - head * NA4;
        const size_t a = (size_t)head * HEAD_STRIDE + (size_t)rem * 4;
        *(f32x4*)(out + a) = *(const f32x4*)(in + a);
    }

    for (int idx = tid0; idx < NB_ALL; idx += stride) {
        const int head = idx / (5400 * NQB);
        const int rem  = idx - head * (5400 * NQB);
        const int row  = rem / NQB;
        const int k    = rem - row * NQB;
        const unsigned rowbase = (unsigned)head * HEAD_STRIDE
                               + (unsigned)(N_TEXT + row) * N_TOKEN;
        const int s = (int)(rowbase & 3u);            // 0 or 2
        const unsigned a0 = rowbase - s + (unsigned)(k << 2);
        const int c0 = (k << 2) - s;                  // text col of elem 0
        f32x4 v = *(const f32x4*)(in + a0);
        if (c0 >= 0 && c0 + 3 < N_TEXT) {
            *(f32x4*)(out + a0) = v;
        } else {
            if (c0 >= 0 && c0 < N_TEXT)         out[a0]     = v.x;
            if (c0 + 1 >= 0 && c0 + 1 < N_TEXT) out[a0 + 1] = v.y;
            if (c0 + 2 < N_TEXT)                out[a0 + 2] = v.z;
            if (c0 + 3 < N_TEXT)                out[a0 + 3] = v.w;
        }
    }
}

// ---------------------------------------------------------------------------
__global__ __launch_bounds__(1024)
void qam_fused(const float* __restrict__ in, float* __restrict__ out) {
    const int b = blockIdx.x;
    if (b < 729)        tile_fused<200, 27, 10>(in, out, b,        0);
    else if (b < 2025)  tile_fused<150, 36, 6> (in, out, b - 729,  1);
    else if (b < 4050)  tile_fused<120, 45, 4> (in, out, b - 2025, 2);
    else if (b < NTILE) tile_fused<100, 54, 3> (in, out, b - 4050, 3);
    else                text_copy(in, out, b - NTILE);
}

extern "C" void kernel_launch(void* const* d_in, const int* in_sizes, int n_in,
                              void* d_out, int out_size, void* d_ws, size_t ws_size,
                              hipStream_t stream) {
    const float* x = (const float*)d_in[0];
    float* out     = (float*)d_out;
    qam_fused<<<NTILE + TEXT_BLOCKS, 1024, 0, stream>>>(x, out);
}